// Round 1
// baseline (193.432 us; speedup 1.0000x reference)
//
#include <hip/hip_runtime.h>
#include <math.h>

// Problem constants (from reference)
#define NN 1024      // N
#define DD 64        // D
#define TT 2048      // T
#define UDEC 0.97f
#define EPS 1e-6f
// Phase-D chunking (rho/a* path)
#define CC 64        // chunk length along t
#define NCH 32       // TT/CC
#define NSL 8        // N-slices for partial Gram/inter
#define SLW 128      // slice width (NN/NSL)
// X prefix-scan chunking
#define C2 32
#define NC2 64       // TT/C2

// ---------------------------------------------------------------------------
// K1: per-scan-chunk X computation: r[t,n]=relu(dot(Vemb[t],Dx[n]));
//     Xp = inclusive intra-chunk prefix; S = chunk totals.
__global__ __launch_bounds__(256) void k_xscan(
    const float* __restrict__ Dx, const float* __restrict__ temb,
    const int* __restrict__ toks, float* __restrict__ Xp, float* __restrict__ S)
{
    const int cs = blockIdx.y;                     // 0..NC2-1
    const int n  = blockIdx.x * 256 + threadIdx.x; // 0..NN-1
    __shared__ float Vs[C2][DD];                   // 8 KB, gathered embeddings
    for (int i = threadIdx.x; i < C2 * DD; i += 256) {
        int s = i >> 6, d = i & 63;
        Vs[s][d] = temb[toks[cs * C2 + s] * DD + d];
    }
    __syncthreads();
    float dxr[DD];
    const float4* dx4 = reinterpret_cast<const float4*>(Dx + n * DD);
#pragma unroll
    for (int j = 0; j < DD / 4; ++j) {
        float4 v = dx4[j];
        dxr[4*j] = v.x; dxr[4*j+1] = v.y; dxr[4*j+2] = v.z; dxr[4*j+3] = v.w;
    }
    float run = 0.f;
    for (int s = 0; s < C2; ++s) {
        const float4* vr = reinterpret_cast<const float4*>(&Vs[s][0]); // broadcast reads
        float a0 = 0.f, a1 = 0.f, a2 = 0.f, a3 = 0.f;
#pragma unroll
        for (int j = 0; j < DD / 4; ++j) {
            float4 v = vr[j];
            a0 += v.x * dxr[4*j];     a1 += v.y * dxr[4*j+1];
            a2 += v.z * dxr[4*j+2];   a3 += v.w * dxr[4*j+3];
        }
        float r = (a0 + a1) + (a2 + a3);
        run += fmaxf(r, 0.f);
        Xp[(cs * C2 + s) * NN + n] = run;
    }
    S[cs * NN + n] = run;
}

// K2: exclusive scan of chunk totals (+x0) -> per-chunk base B. 1024 threads.
__global__ __launch_bounds__(256) void k_base(
    const float* __restrict__ S, const float* __restrict__ x0, float* __restrict__ Bb)
{
    const int n = blockIdx.x * 256 + threadIdx.x; // grid=4
    float acc = x0[n];
    for (int cs = 0; cs < NC2; ++cs) {
        Bb[cs * NN + n] = acc;
        acc += S[cs * NN + n];
    }
}

// True X[t][n] = Xp[t][n] + Bb[t/C2][n] (fixed up on the fly by consumers).

// K3: per-chunk rank-collapse M_c[d][n] = sum_{s_l} U^(CC-s_l) v[c0+s_l][d] * x[c0+s_l][n]
__global__ __launch_bounds__(256) void k_M(
    const float* __restrict__ Xp, const float* __restrict__ Bb,
    const float* __restrict__ temb, const int* __restrict__ toks, float* __restrict__ M)
{
    const int c = blockIdx.y, q = blockIdx.x;
    __shared__ float Xs[CC][SLW + 1];   // +1 pad: lane-varying-n reads conflict-free
    __shared__ float Vw[CC][DD];        // unpadded: broadcast float4 reads
    __shared__ float pw[CC + 1];
    const int tid = threadIdx.x;
    if (tid <= CC) pw[tid] = powf(UDEC, (float)tid);
    __syncthreads();
    for (int i = tid; i < CC * SLW; i += 256) {
        int s = i / SLW, n = i % SLW;
        int t = c * CC + s, gn = q * SLW + n;
        Xs[s][n] = Xp[t * NN + gn] + Bb[(t >> 5) * NN + gn];
    }
    for (int i = tid; i < CC * DD; i += 256) {
        int s = i >> 6, d = i & 63;
        Vw[s][d] = temb[toks[c * CC + s] * DD + d] * pw[CC - s];
    }
    __syncthreads();
    const int n_l = tid & 127;
    const int dh  = tid >> 7;           // 0/1 -> d = dh*32 + k
    float acc[32];
#pragma unroll
    for (int k = 0; k < 32; ++k) acc[k] = 0.f;
    for (int s = 0; s < CC; ++s) {
        float xv = Xs[s][n_l];
        const float4* vr = reinterpret_cast<const float4*>(&Vw[s][dh * 32]);
#pragma unroll
        for (int k8 = 0; k8 < 8; ++k8) {
            float4 v = vr[k8];
            acc[4*k8]   += v.x * xv;  acc[4*k8+1] += v.y * xv;
            acc[4*k8+2] += v.z * xv;  acc[4*k8+3] += v.w * xv;
        }
    }
    for (int k = 0; k < 32; ++k)
        M[(c * DD + dh * 32 + k) * NN + q * SLW + n_l] = acc[k];
}

// K4: elementwise scan over chunks: Rho[c] = state entering chunk c.
//     Rho[0]=rho0; Rho[c+1] = U^CC * Rho[c] + M[c].
__global__ __launch_bounds__(256) void k_rho(
    const float* __restrict__ M, const float* __restrict__ rho0, float* __restrict__ Rho)
{
    const int el = blockIdx.x * 256 + threadIdx.x;  // grid = DD*NN/256
    float acc = rho0[el];
    const float uc = powf(UDEC, (float)CC);
    for (int c = 0; c < NCH; ++c) {
        Rho[c * (DD * NN) + el] = acc;
        acc = fmaf(acc, uc, M[c * (DD * NN) + el]);
    }
}

// K5: per (chunk, N-slice): partial Gram Gp[t][s]=sum_n x_t x_s and
//     partial inter Pp[t][d]=sum_n Rho[c][d][n] x_t[n].  4x4 register tiles.
__global__ __launch_bounds__(256) void k_gram(
    const float* __restrict__ Xp, const float* __restrict__ Bb,
    const float* __restrict__ Rho, float* __restrict__ Gp, float* __restrict__ Pp)
{
    const int c = blockIdx.y, q = blockIdx.x;
    __shared__ float Xs[CC][SLW + 1];
    __shared__ float Rs[DD][SLW + 1];
    const int tid = threadIdx.x;
    for (int i = tid; i < CC * SLW; i += 256) {
        int s = i / SLW, n = i % SLW;
        int t = c * CC + s, gn = q * SLW + n;
        Xs[s][n] = Xp[t * NN + gn] + Bb[(t >> 5) * NN + gn];
        Rs[s][n] = Rho[(c * DD + s) * NN + gn];     // DD==CC==64 rows
    }
    __syncthreads();
    const int ti = tid >> 4;   // 0..15 -> t = ti*4+a
    const int sj = tid & 15;   // 0..15 -> s/d = sj*4+b
    float acc[16];
#pragma unroll
    for (int k = 0; k < 16; ++k) acc[k] = 0.f;
    for (int n = 0; n < SLW; ++n) {
        float xt[4], xs[4];
#pragma unroll
        for (int a = 0; a < 4; ++a) xt[a] = Xs[ti * 4 + a][n];
#pragma unroll
        for (int b = 0; b < 4; ++b) xs[b] = Xs[sj * 4 + b][n];
#pragma unroll
        for (int a = 0; a < 4; ++a)
#pragma unroll
            for (int b = 0; b < 4; ++b) acc[a * 4 + b] += xt[a] * xs[b];
    }
    {
        float* base = Gp + ((size_t)(c * NSL + q) * CC) * CC;
#pragma unroll
        for (int a = 0; a < 4; ++a)
            *reinterpret_cast<float4*>(base + (ti * 4 + a) * CC + sj * 4) =
                make_float4(acc[a*4], acc[a*4+1], acc[a*4+2], acc[a*4+3]);
    }
#pragma unroll
    for (int k = 0; k < 16; ++k) acc[k] = 0.f;
    for (int n = 0; n < SLW; ++n) {
        float xt[4], rv[4];
#pragma unroll
        for (int a = 0; a < 4; ++a) xt[a] = Xs[ti * 4 + a][n];
#pragma unroll
        for (int b = 0; b < 4; ++b) rv[b] = Rs[sj * 4 + b][n];
#pragma unroll
        for (int a = 0; a < 4; ++a)
#pragma unroll
            for (int b = 0; b < 4; ++b) acc[a * 4 + b] += xt[a] * rv[b];
    }
    {
        float* base = Pp + ((size_t)(c * NSL + q) * CC) * DD;
#pragma unroll
        for (int a = 0; a < 4; ++a)
            *reinterpret_cast<float4*>(base + (ti * 4 + a) * DD + sj * 4) =
                make_float4(acc[a*4], acc[a*4+1], acc[a*4+2], acc[a*4+3]);
    }
}

// K6: per chunk: reduce slices, A*[t][d] = U^t_l * P[t][d]
//     + sum_{s<t_l} U^(t_l-s) G[t][s] Vemb[s][d]; then rowwise LN (ddof=1).
__global__ __launch_bounds__(256) void k_astar(
    const float* __restrict__ Gp, const float* __restrict__ Pp,
    const float* __restrict__ temb, const int* __restrict__ toks,
    float* __restrict__ LNA)
{
    const int c = blockIdx.x;
    __shared__ float G[CC][CC + 1];
    __shared__ float P[CC][DD + 1];
    __shared__ float Ve[CC][DD];
    __shared__ float As[CC][DD + 1];
    __shared__ float pw[CC + 1];
    __shared__ float mrow[CC], srow[CC];
    const int tid = threadIdx.x;
    if (tid <= CC) pw[tid] = powf(UDEC, (float)tid);
    for (int i = tid; i < CC * CC; i += 256) {
        int t = i >> 6, s = i & 63;
        float ag = 0.f, ap = 0.f;
#pragma unroll
        for (int qq = 0; qq < NSL; ++qq) {
            ag += Gp[((size_t)(c * NSL + qq) * CC + t) * CC + s];
            ap += Pp[((size_t)(c * NSL + qq) * CC + t) * DD + s];
        }
        G[t][s] = ag; P[t][s] = ap;
    }
    for (int i = tid; i < CC * DD; i += 256) {
        int s = i >> 6, d = i & 63;
        Ve[s][d] = temb[toks[c * CC + s] * DD + d];
    }
    __syncthreads();
    const int t_l = tid >> 2;   // 0..63
    const int qq  = tid & 3;    // d-quarter
    float acc[16];
#pragma unroll
    for (int j = 0; j < 16; ++j) acc[j] = pw[t_l] * P[t_l][qq * 16 + j];
    for (int s = 0; s < t_l; ++s) {
        float wv = pw[t_l - s] * G[t_l][s];
        const float4* ver = reinterpret_cast<const float4*>(&Ve[s][qq * 16]);
#pragma unroll
        for (int k = 0; k < 4; ++k) {
            float4 v = ver[k];
            acc[4*k]   += wv * v.x;  acc[4*k+1] += wv * v.y;
            acc[4*k+2] += wv * v.z;  acc[4*k+3] += wv * v.w;
        }
    }
#pragma unroll
    for (int j = 0; j < 16; ++j) As[t_l][qq * 16 + j] = acc[j];
    __syncthreads();
    if (tid < CC) {
        float m = 0.f;
#pragma unroll
        for (int d = 0; d < DD; ++d) m += As[tid][d];
        m *= (1.f / DD);
        float v = 0.f;
#pragma unroll
        for (int d = 0; d < DD; ++d) { float z = As[tid][d] - m; v += z * z; }
        mrow[tid] = m;
        srow[tid] = 1.f / (sqrtf(v / (DD - 1)) + EPS);
    }
    __syncthreads();
    for (int i = tid; i < CC * DD; i += 256) {
        int t = i >> 6, d = i & 63;
        LNA[(c * CC + t) * DD + d] = (As[t][d] - mrow[t]) * srow[t];
    }
}

// K7: y[t][n] = relu(dot(LNA[t], Dy[n])) * relu(x[t][n])
__global__ __launch_bounds__(256) void k_y(
    const float* __restrict__ LNA, const float* __restrict__ Dy,
    const float* __restrict__ Xp, const float* __restrict__ Bb,
    float* __restrict__ ys)
{
    const int tt = blockIdx.y;                       // 8-row tile
    const int n  = blockIdx.x * 256 + threadIdx.x;
    __shared__ float L[8][DD];
    for (int i = threadIdx.x; i < 8 * DD; i += 256) L[i >> 6][i & 63] = LNA[tt * 8 * DD + i];
    __syncthreads();
    float dyr[DD];
    const float4* dy4 = reinterpret_cast<const float4*>(Dy + n * DD);
#pragma unroll
    for (int j = 0; j < 16; ++j) {
        float4 v = dy4[j];
        dyr[4*j] = v.x; dyr[4*j+1] = v.y; dyr[4*j+2] = v.z; dyr[4*j+3] = v.w;
    }
#pragma unroll
    for (int t = 0; t < 8; ++t) {
        const float4* lr = reinterpret_cast<const float4*>(&L[t][0]);
        float a0 = 0.f, a1 = 0.f, a2 = 0.f, a3 = 0.f;
#pragma unroll
        for (int j = 0; j < 16; ++j) {
            float4 v = lr[j];
            a0 += v.x * dyr[4*j];   a1 += v.y * dyr[4*j+1];
            a2 += v.z * dyr[4*j+2]; a3 += v.w * dyr[4*j+3];
        }
        float yc = (a0 + a1) + (a2 + a3);
        int tg = tt * 8 + t;
        float xv = Xp[tg * NN + n] + Bb[(tg >> 5) * NN + n];
        ys[tg * NN + n] = fmaxf(yc, 0.f) * fmaxf(xv, 0.f);
    }
}

// K8: vs[t] = LN(E @ y[t]) for an 8-row tile per block.
__global__ __launch_bounds__(256) void k_v(
    const float* __restrict__ ys, const float* __restrict__ E, float* __restrict__ vs)
{
    const int tt = blockIdx.x;
    __shared__ float Ys[8][NN];          // 32 KB
    __shared__ float pre[8][DD + 1];
    __shared__ float mrow[8], srow[8];
    const int tid = threadIdx.x;
    for (int i = tid; i < 8 * NN; i += 256) Ys[i >> 10][i & 1023] = ys[tt * 8 * NN + i];
    __syncthreads();
    const int d  = tid & 63;
    const int tq = tid >> 6;             // 0..3 -> t = tq*2 + {0,1}
    const int t0 = tq * 2;
    const float4* e4 = reinterpret_cast<const float4*>(E + d * NN);
    float a00=0,a01=0,a02=0,a03=0, a10=0,a11=0,a12=0,a13=0;
    for (int j = 0; j < NN / 4; ++j) {
        float4 ev  = e4[j];
        float4 y0v = *reinterpret_cast<const float4*>(&Ys[t0][4 * j]);     // broadcast
        float4 y1v = *reinterpret_cast<const float4*>(&Ys[t0 + 1][4 * j]); // broadcast
        a00 += ev.x * y0v.x; a01 += ev.y * y0v.y; a02 += ev.z * y0v.z; a03 += ev.w * y0v.w;
        a10 += ev.x * y1v.x; a11 += ev.y * y1v.y; a12 += ev.z * y1v.z; a13 += ev.w * y1v.w;
    }
    pre[t0][d]     = (a00 + a01) + (a02 + a03);
    pre[t0 + 1][d] = (a10 + a11) + (a12 + a13);
    __syncthreads();
    if (tid < 8) {
        float m = 0.f;
#pragma unroll
        for (int dd2 = 0; dd2 < DD; ++dd2) m += pre[tid][dd2];
        m *= (1.f / DD);
        float v = 0.f;
#pragma unroll
        for (int dd2 = 0; dd2 < DD; ++dd2) { float z = pre[tid][dd2] - m; v += z * z; }
        mrow[tid] = m;
        srow[tid] = 1.f / (sqrtf(v / (DD - 1)) + EPS);
    }
    __syncthreads();
    for (int i = tid; i < 8 * DD; i += 256) {
        int t = i >> 6, dd2 = i & 63;
        vs[(tt * 8 + t) * DD + dd2] = (pre[t][dd2] - mrow[t]) * srow[t];
    }
}

// ---------------------------------------------------------------------------
extern "C" void kernel_launch(void* const* d_in, const int* in_sizes, int n_in,
                              void* d_out, int out_size, void* d_ws, size_t ws_size,
                              hipStream_t stream) {
    (void)in_sizes; (void)n_in; (void)out_size; (void)ws_size;
    const float* E    = (const float*)d_in[0];   // [D,N]
    const float* Dx   = (const float*)d_in[1];   // [N,D]
    const float* Dy   = (const float*)d_in[2];   // [N,D]
    const float* temb = (const float*)d_in[3];   // [V,D]
    const float* x0   = (const float*)d_in[4];   // [N]
    const float* rho0 = (const float*)d_in[5];   // [D,N]
    const int*   toks = (const int*)d_in[6];     // [T]

    float* ys = (float*)d_out;                   // [T,N]
    float* vs = ys + (size_t)TT * NN;            // [T,D]

    float* w   = (float*)d_ws;                   // needs ~25 MiB
    float* Xp  = w;                              // TT*NN      intra-chunk prefix
    float* S   = Xp  + (size_t)TT * NN;          // NC2*NN
    float* Bb  = S   + (size_t)NC2 * NN;         // NC2*NN
    float* M   = Bb  + (size_t)NC2 * NN;         // NCH*DD*NN
    float* Rho = M   + (size_t)NCH * DD * NN;    // NCH*DD*NN
    float* LNA = Rho + (size_t)NCH * DD * NN;    // TT*DD
    // Gp/Pp alias M (M is dead after k_rho; Gp+Pp == M's footprint exactly)
    float* Gp = M;
    float* Pp = M + (size_t)NCH * NSL * CC * CC;

    k_xscan<<<dim3(4, NC2),  256, 0, stream>>>(Dx, temb, toks, Xp, S);
    k_base <<<dim3(4),       256, 0, stream>>>(S, x0, Bb);
    k_M    <<<dim3(NSL, NCH),256, 0, stream>>>(Xp, Bb, temb, toks, M);
    k_rho  <<<dim3(DD*NN/256),256,0, stream>>>(M, rho0, Rho);
    k_gram <<<dim3(NSL, NCH),256, 0, stream>>>(Xp, Bb, Rho, Gp, Pp);
    k_astar<<<dim3(NCH),     256, 0, stream>>>(Gp, Pp, temb, toks, LNA);
    k_y    <<<dim3(4, TT/8), 256, 0, stream>>>(LNA, Dy, Xp, Bb, ys);
    k_v    <<<dim3(TT/8),    256, 0, stream>>>(ys, E, vs);
}